// Round 8
// baseline (419.973 us; speedup 1.0000x reference)
//
#include <hip/hip_runtime.h>
#include <hip/hip_bf16.h>
#include <math.h>

#define HCH    512      // H * HID = 4 * 128
#define OUTD   128
#define N0CAT  2048     // L0 fused: q|k|v|s   (s = 512)
#define N1CAT  1664     // L1 fused: q|k|v|s1  (s = 128)
#define P0STR  1024     // P0 row: q(512)|s(512)
#define P1STR  640      // P1 row: q(512)|s(128)
#define KVW    1024     // fp8 KV row: k(512B) | v(512B)

typedef __attribute__((ext_vector_type(8))) short short8v;
typedef __attribute__((ext_vector_type(8))) unsigned short ushort8v;
typedef __attribute__((ext_vector_type(4))) float floatx4;
typedef __attribute__((ext_vector_type(2))) float floatx2;
typedef __attribute__((ext_vector_type(2))) unsigned int uintx2;

__device__ inline float bf2f(unsigned short u) {
    return __uint_as_float(((unsigned)u) << 16);
}

template <bool HI>
__device__ inline floatx2 fp8x2_to_f32(unsigned int w) {
    return __builtin_amdgcn_cvt_pk_f32_fp8(w, HI);
}

__device__ inline unsigned char f32_to_fp8(float v) {
    return (unsigned char)(__builtin_amdgcn_cvt_pk_fp8_f32(v, v, 0, false) & 0xff);
}

// async global->LDS, 16 B per lane; lds dst = wave-uniform base + lane*16
__device__ inline void gload_lds16(const void* g, void* l) {
    __builtin_amdgcn_global_load_lds(
        (const __attribute__((address_space(1))) unsigned int*)g,
        (__attribute__((address_space(3))) unsigned int*)l, 16, 0, 0);
}

// ---------------- CSR build ----------------

__global__ void hist_kernel(const int* __restrict__ dst, int* __restrict__ deg, int E) {
    int e = blockIdx.x * 256 + threadIdx.x;
    if (e < E) atomicAdd(&deg[dst[e]], 1);
}

__global__ __launch_bounds__(1024) void scan_kernel(const int* __restrict__ deg,
                                                    int* __restrict__ indptr,
                                                    int* __restrict__ cursor, int n) {
    __shared__ int wavesum[16];
    __shared__ int carry_s;
    int t = threadIdx.x;
    int lane = t & 63;
    int w = t >> 6;
    if (t == 0) carry_s = 0;
    __syncthreads();
    for (int base = 0; base < n; base += 4096) {
        int idx = base + t * 4;
        int v0 = (idx + 0 < n) ? deg[idx + 0] : 0;
        int v1 = (idx + 1 < n) ? deg[idx + 1] : 0;
        int v2 = (idx + 2 < n) ? deg[idx + 2] : 0;
        int v3 = (idx + 3 < n) ? deg[idx + 3] : 0;
        int s1 = v0 + v1, s2 = s1 + v2, tot = s2 + v3;
        int x = tot;
        #pragma unroll
        for (int off = 1; off < 64; off <<= 1) {
            int y = __shfl_up(x, off);
            if (lane >= off) x += y;
        }
        if (lane == 63) wavesum[w] = x;
        __syncthreads();
        int woff = 0;
        for (int i = 0; i < w; i++) woff += wavesum[i];
        int carry = carry_s;
        int excl = carry + woff + x - tot;
        if (idx + 0 < n) { indptr[idx + 0] = excl;      cursor[idx + 0] = excl; }
        if (idx + 1 < n) { indptr[idx + 1] = excl + v0; cursor[idx + 1] = excl + v0; }
        if (idx + 2 < n) { indptr[idx + 2] = excl + s1; cursor[idx + 2] = excl + s1; }
        if (idx + 3 < n) { indptr[idx + 3] = excl + s2; cursor[idx + 3] = excl + s2; }
        __syncthreads();
        if (t == 0) {
            int s = 0;
            #pragma unroll
            for (int i = 0; i < 16; i++) s += wavesum[i];
            carry_s = carry + s;
        }
        __syncthreads();
    }
    if (t == 0) indptr[n] = carry_s;
}

__global__ void scatter_kernel(const int* __restrict__ src, const int* __restrict__ dst,
                               int* __restrict__ cursor, int* __restrict__ srcs_sorted, int E) {
    int e = blockIdx.x * 256 + threadIdx.x;
    if (e < E) {
        int d = dst[e];
        int pos = atomicAdd(&cursor[d], 1);
        srcs_sorted[pos] = src[e];
    }
}

// ---------------- prep: cast + transpose + concat weights ----------------

__global__ void cast_bf16_kernel(const float* __restrict__ in, __hip_bfloat16* __restrict__ out, int n) {
    int i = blockIdx.x * 256 + threadIdx.x;
    if (i < n) out[i] = __float2bfloat16(in[i]);
}

// L0: Wt[2048][128] from Wq/Wk/Wv/Ws [128][512]; bcat[2048]
__global__ void prep0_kernel(const float* __restrict__ Wq, const float* __restrict__ Wk,
                             const float* __restrict__ Wv, const float* __restrict__ Wsk,
                             const float* __restrict__ bq, const float* __restrict__ bk,
                             const float* __restrict__ bv, const float* __restrict__ bsk,
                             __hip_bfloat16* __restrict__ Wt, float* __restrict__ bcat) {
    int i = blockIdx.x * 256 + threadIdx.x;
    if (i < N0CAT * 128) {
        int n = i >> 7, k = i & 127;
        int sel = n >> 9, col = n & 511;
        const float* W = (sel == 0) ? Wq : (sel == 1) ? Wk : (sel == 2) ? Wv : Wsk;
        Wt[i] = __float2bfloat16(W[k * 512 + col]);
    }
    if (i < N0CAT) {
        int sel = i >> 9, col = i & 511;
        const float* b = (sel == 0) ? bq : (sel == 1) ? bk : (sel == 2) ? bv : bsk;
        bcat[i] = b[col];
    }
}

// L1: Wt[1664][512] from Wq/Wk/Wv [512][512] + Ws1 [512][128]; bcat[1664]
__global__ void prep1_kernel(const float* __restrict__ Wq, const float* __restrict__ Wk,
                             const float* __restrict__ Wv, const float* __restrict__ Wsk,
                             const float* __restrict__ bq, const float* __restrict__ bk,
                             const float* __restrict__ bv, const float* __restrict__ bsk,
                             __hip_bfloat16* __restrict__ Wt, float* __restrict__ bcat) {
    int i = blockIdx.x * 256 + threadIdx.x;
    if (i < N1CAT * 512) {
        int n = i >> 9, k = i & 511;
        float val;
        if (n < 1536) {
            int sel = n >> 9, col = n & 511;
            const float* W = (sel == 0) ? Wq : (sel == 1) ? Wk : Wv;
            val = W[k * 512 + col];
        } else {
            val = Wsk[k * 128 + (n - 1536)];
        }
        Wt[i] = __float2bfloat16(val);
    }
    if (i < N1CAT) {
        float bv_;
        if (i < 1536) {
            int sel = i >> 9, col = i & 511;
            const float* b = (sel == 0) ? bq : (sel == 1) ? bk : bv;
            bv_ = b[col];
        } else {
            bv_ = bsk[i - 1536];
        }
        bcat[i] = bv_;
    }
}

// ---------------- bf16 MFMA GEMM, async-LDS staging, split epilogue ----------------
// C = A[M,K] @ Bt[Nd,K]^T + bias. Columns: [0,512) q -> P; [512,1536) k|v -> KV8 fp8;
// [1536,Nd) s -> P offset 512+. Grid f = nt*mt_pad + mt => xcd(f%8)==mt%8.
// A must have mt_pad*BM valid (readable) rows; rows >= M produce garbage, store-guarded.

#define BM 128
#define BN 128
#define BK 64

__global__ __launch_bounds__(256) void gemm_mfma(const __hip_bfloat16* __restrict__ A,
                                                 const __hip_bfloat16* __restrict__ Bt,
                                                 const float* __restrict__ bias,
                                                 __hip_bfloat16* __restrict__ P,
                                                 int pstride,
                                                 unsigned char* __restrict__ KV8,
                                                 int M, int K, int Nd, int mt_pad) {
    __shared__ __hip_bfloat16 As[BM][BK];
    __shared__ __hip_bfloat16 Bs[BN][BK];
    int f = blockIdx.x;
    int mt = f % mt_pad, nt = f / mt_pad;
    int bm = mt * BM, bn = nt * BN;
    if (bm >= M) return;
    int t = threadIdx.x;
    int lane = t & 63, w = t >> 6;
    int quad = lane >> 4, l16 = lane & 15;
    int wm = (w >> 1) * 64, wn = (w & 1) * 64;

    // async staging geometry: thread t covers (row = i*32 + w*8 + lane/8, col = (lane&7)*8)
    const char* Ab = (const char*)(A + (size_t)(bm + w * 8 + (lane >> 3)) * K + (lane & 7) * 8);
    const char* Bb = (const char*)(Bt + (size_t)(bn + w * 8 + (lane >> 3)) * K + (lane & 7) * 8);
    char* Al = (char*)&As[0][0] + w * 1024;
    char* Bl = (char*)&Bs[0][0] + w * 1024;

    floatx4 acc[4][4];
    #pragma unroll
    for (int i = 0; i < 4; i++)
        #pragma unroll
        for (int j = 0; j < 4; j++)
            acc[i][j] = (floatx4)0.0f;

    for (int k0 = 0; k0 < K; k0 += BK) {
        __syncthreads();   // previous compute done before overwrite
        #pragma unroll
        for (int i = 0; i < 4; i++) {
            size_t go = ((size_t)i * 32 * K + k0) * 2;
            gload_lds16(Ab + go, Al + i * 4096);
            gload_lds16(Bb + go, Bl + i * 4096);
        }
        __syncthreads();   // vmcnt drained -> LDS visible
        #pragma unroll
        for (int ks = 0; ks < BK; ks += 32) {
            short8v af[4], bfr[4];
            #pragma unroll
            for (int i = 0; i < 4; i++)
                af[i] = *(const short8v*)&As[wm + i * 16 + l16][ks + quad * 8];
            #pragma unroll
            for (int j = 0; j < 4; j++)
                bfr[j] = *(const short8v*)&Bs[wn + j * 16 + l16][ks + quad * 8];
            #pragma unroll
            for (int i = 0; i < 4; i++)
                #pragma unroll
                for (int j = 0; j < 4; j++)
                    acc[i][j] = __builtin_amdgcn_mfma_f32_16x16x32_bf16(af[i], bfr[j], acc[i][j], 0, 0, 0);
        }
    }

    #pragma unroll
    for (int i = 0; i < 4; i++) {
        #pragma unroll
        for (int j = 0; j < 4; j++) {
            int col = bn + wn + j * 16 + l16;
            float bb = bias[col];
            if (col < 512) {
                #pragma unroll
                for (int r = 0; r < 4; r++) {
                    int row = bm + wm + i * 16 + quad * 4 + r;
                    if (row < M)
                        P[(size_t)row * pstride + col] = __float2bfloat16(acc[i][j][r] + bb);
                }
            } else if (col < 1536) {
                #pragma unroll
                for (int r = 0; r < 4; r++) {
                    int row = bm + wm + i * 16 + quad * 4 + r;
                    if (row < M)
                        KV8[(size_t)row * KVW + (col - 512)] = f32_to_fp8(acc[i][j][r] + bb);
                }
            } else {
                #pragma unroll
                for (int r = 0; r < 4; r++) {
                    int row = bm + wm + i * 16 + quad * 4 + r;
                    if (row < M)
                        P[(size_t)row * pstride + 512 + (col - 1536)] = __float2bfloat16(acc[i][j][r] + bb);
                }
            }
        }
    }
}

// ---------------- attention: fp8 K/V gather ----------------
// P row: [ q(512) | s ], KV8 row: [ k8(512B) | v8(512B) ].
// mode 0: out_b[n,512] = relu(attn_concat + s)   (bf16)
// mode 1: out_f[n,128] = mean_heads(attn) + s    (f32)

#define PF 4

__global__ __launch_bounds__(256) void attn_kernel(const __hip_bfloat16* __restrict__ P,
                                                   int pstride,
                                                   const unsigned char* __restrict__ KV8,
                                                   const int* __restrict__ indptr,
                                                   const int* __restrict__ srcs,
                                                   __hip_bfloat16* __restrict__ out_b,
                                                   float* __restrict__ out_f,
                                                   int n_nodes, int mode) {
    int wave = threadIdx.x >> 6;
    int lane = threadIdx.x & 63;
    int node = blockIdx.x * 4 + wave;
    if (node >= n_nodes) return;
    const float scale = 0.08838834764831845f;  // 1/sqrt(128)

    const __hip_bfloat16* Prow = P + (size_t)node * pstride;
    float qf[8];
    {
        ushort8v qu = *(const ushort8v*)(Prow + lane * 8);
        #pragma unroll
        for (int j = 0; j < 8; j++) qf[j] = bf2f(qu[j]);
    }

    float m = -INFINITY, l = 0.f;
    float acc[8] = {0.f, 0.f, 0.f, 0.f, 0.f, 0.f, 0.f, 0.f};

    int e0 = indptr[node], e1 = indptr[node + 1];
    const unsigned char* Kb = KV8 + lane * 8;        // K bytes for this lane

    uintx2 kb[PF], vb[PF];
    #pragma unroll
    for (int i = 0; i < PF; i++) {
        if (e0 + i < e1) {
            int s = srcs[e0 + i];
            const unsigned char* kp = Kb + (size_t)s * KVW;
            kb[i] = *(const uintx2*)kp;
            vb[i] = *(const uintx2*)(kp + 512);
        }
    }

    for (int e = e0; e < e1; e += PF) {
        #pragma unroll
        for (int i = 0; i < PF; i++) {
            int ce = e + i;
            if (ce < e1) {
                uintx2 ku = kb[i];
                uintx2 vu = vb[i];
                int pe = ce + PF;
                if (pe < e1) {
                    int s = srcs[pe];
                    const unsigned char* kp = Kb + (size_t)s * KVW;
                    kb[i] = *(const uintx2*)kp;
                    vb[i] = *(const uintx2*)(kp + 512);
                }
                floatx2 k01 = fp8x2_to_f32<false>(ku[0]);
                floatx2 k23 = fp8x2_to_f32<true >(ku[0]);
                floatx2 k45 = fp8x2_to_f32<false>(ku[1]);
                floatx2 k67 = fp8x2_to_f32<true >(ku[1]);
                float part = qf[0] * k01[0] + qf[1] * k01[1]
                           + qf[2] * k23[0] + qf[3] * k23[1]
                           + qf[4] * k45[0] + qf[5] * k45[1]
                           + qf[6] * k67[0] + qf[7] * k67[1];
                part += __shfl_xor(part, 1);
                part += __shfl_xor(part, 2);
                part += __shfl_xor(part, 4);
                part += __shfl_xor(part, 8);
                float logit = part * scale;
                float mnew = fmaxf(m, logit);
                float corr = __expf(m - mnew);
                float p = __expf(logit - mnew);
                l = l * corr + p;
                m = mnew;
                floatx2 v01 = fp8x2_to_f32<false>(vu[0]);
                floatx2 v23 = fp8x2_to_f32<true >(vu[0]);
                floatx2 v45 = fp8x2_to_f32<false>(vu[1]);
                floatx2 v67 = fp8x2_to_f32<true >(vu[1]);
                acc[0] = acc[0] * corr + p * v01[0];
                acc[1] = acc[1] * corr + p * v01[1];
                acc[2] = acc[2] * corr + p * v23[0];
                acc[3] = acc[3] * corr + p * v23[1];
                acc[4] = acc[4] * corr + p * v45[0];
                acc[5] = acc[5] * corr + p * v45[1];
                acc[6] = acc[6] * corr + p * v67[0];
                acc[7] = acc[7] * corr + p * v67[1];
            }
        }
    }
    float inv = (l > 0.f) ? 1.f / l : 0.f;

    if (mode == 0) {
        ushort8v su = *(const ushort8v*)(Prow + 512 + lane * 8);
        ushort8v o;
        #pragma unroll
        for (int j = 0; j < 8; j++) {
            float r = fmaxf(acc[j] * inv + bf2f(su[j]), 0.f);
            o[j] = (unsigned short)__bfloat16_as_ushort(__float2bfloat16(r));
        }
        *(ushort8v*)(out_b + (size_t)node * HCH + lane * 8) = o;
    } else {
        float r[8];
        #pragma unroll
        for (int j = 0; j < 8; j++) {
            r[j] = acc[j] * inv;
            r[j] += __shfl_xor(r[j], 16);
            r[j] += __shfl_xor(r[j], 32);
            r[j] *= 0.25f;
        }
        if (lane < 16) {
            const __hip_bfloat16* sp = Prow + 512 + lane * 8;
            float* op = out_f + (size_t)node * OUTD + lane * 8;
            #pragma unroll
            for (int j = 0; j < 8; j++) op[j] = r[j] + bf2f(__bfloat16_as_ushort(sp[j]));
        }
    }
}

// ---------------- launch ----------------

static inline size_t align256(size_t x) { return (x + 255) & ~(size_t)255; }

extern "C" void kernel_launch(void* const* d_in, const int* in_sizes, int n_in,
                              void* d_out, int out_size, void* d_ws, size_t ws_size,
                              hipStream_t stream) {
    const float* x   = (const float*)d_in[0];
    const int*   ei  = (const int*)d_in[1];
    const float* Wq0 = (const float*)d_in[2];  const float* bq0 = (const float*)d_in[3];
    const float* Wk0 = (const float*)d_in[4];  const float* bk0 = (const float*)d_in[5];
    const float* Wv0 = (const float*)d_in[6];  const float* bv0 = (const float*)d_in[7];
    const float* Ws0 = (const float*)d_in[8];  const float* bs0 = (const float*)d_in[9];
    const float* Wq1 = (const float*)d_in[10]; const float* bq1 = (const float*)d_in[11];
    const float* Wk1 = (const float*)d_in[12]; const float* bk1 = (const float*)d_in[13];
    const float* Wv1 = (const float*)d_in[14]; const float* bv1 = (const float*)d_in[15];
    const float* Ws1 = (const float*)d_in[16]; const float* bs1 = (const float*)d_in[17];
    float* out = (float*)d_out;

    const int N = in_sizes[0] / 128;        // 20000
    const int E = in_sizes[1] / 2;          // 320000
    const int* src = ei;
    const int* dst = ei + E;

    int mtiles = (N + BM - 1) / BM;          // 157
    int mt_pad = (mtiles + 7) & ~7;          // 160 (mult of 8 -> XCD affinity)
    const int Mpad = mt_pad * BM;            // 20480: A buffers padded for async staging

    char* ws = (char*)d_ws;
    __hip_bfloat16* P0  = (__hip_bfloat16*)ws; ws += align256((size_t)N * P0STR * 2);
    __hip_bfloat16* P1  = P0;                  // alias: P0 dead before P1 written
    __hip_bfloat16* Hbb = (__hip_bfloat16*)ws; ws += align256((size_t)Mpad * HCH * 2);
    __hip_bfloat16* Xb  = (__hip_bfloat16*)ws; ws += align256((size_t)Mpad * 128 * 2);
    unsigned char* KV8  = (unsigned char*)ws;  ws += align256((size_t)N * KVW);
    __hip_bfloat16* Wc0 = (__hip_bfloat16*)ws; ws += align256((size_t)N0CAT * 128 * 2);
    __hip_bfloat16* Wc1 = (__hip_bfloat16*)ws; ws += align256((size_t)N1CAT * 512 * 2);
    float* bc0 = (float*)ws; ws += align256((size_t)N0CAT * 4);
    float* bc1 = (float*)ws; ws += align256((size_t)N1CAT * 4);
    int* deg    = (int*)ws; ws += align256((size_t)N * 4);
    int* cursor = (int*)ws; ws += align256((size_t)N * 4);
    int* indptr = (int*)ws; ws += align256((size_t)(N + 2) * 4);
    int* srcs   = (int*)ws; ws += align256((size_t)E * 4);

    dim3 blk(256);

    // --- CSR build ---
    (void)hipMemsetAsync(deg, 0, (size_t)N * 4, stream);
    hist_kernel<<<(E + 255) / 256, 256, 0, stream>>>(dst, deg, E);
    scan_kernel<<<1, 1024, 0, stream>>>(deg, indptr, cursor, N);
    scatter_kernel<<<(E + 255) / 256, 256, 0, stream>>>(src, dst, cursor, srcs, E);

    // --- prep ---
    cast_bf16_kernel<<<((size_t)N * 128 + 255) / 256, blk, 0, stream>>>(x, Xb, N * 128);
    prep0_kernel<<<(N0CAT * 128 + 255) / 256, blk, 0, stream>>>(Wq0, Wk0, Wv0, Ws0, bq0, bk0, bv0, bs0, Wc0, bc0);
    prep1_kernel<<<(N1CAT * 512 + 255) / 256, blk, 0, stream>>>(Wq1, Wk1, Wv1, Ws1, bq1, bk1, bv1, bs1, Wc1, bc1);

    // --- layer 0: fused projections (q->P0, kv->fp8 KV8, s->P0) + attention ---
    gemm_mfma<<<dim3(mt_pad * (N0CAT / BN)), blk, 0, stream>>>(
        Xb, Wc0, bc0, P0, P0STR, KV8, N, 128, N0CAT, mt_pad);
    attn_kernel<<<(N + 3) / 4, blk, 0, stream>>>(P0, P0STR, KV8, indptr, srcs, Hbb, nullptr, N, 0);

    // --- layer 1: fused projections + attention ---
    gemm_mfma<<<dim3(mt_pad * (N1CAT / BN)), blk, 0, stream>>>(
        Hbb, Wc1, bc1, P1, P1STR, KV8, N, 512, N1CAT, mt_pad);
    attn_kernel<<<(N + 3) / 4, blk, 0, stream>>>(P1, P1STR, KV8, indptr, srcs, nullptr, out, N, 1);
}

// Round 9
// 384.149 us; speedup vs baseline: 1.0933x; 1.0933x over previous
//
#include <hip/hip_runtime.h>
#include <hip/hip_bf16.h>
#include <math.h>

#define HCH    512      // H * HID = 4 * 128
#define OUTD   128
#define N0CAT  2048     // L0 fused: q|k|v|s   (s = 512)
#define N1CAT  1664     // L1 fused: q|k|v|s1  (s = 128)
#define P0STR  1024     // P0 row: q(512)|s(512)
#define P1STR  640      // P1 row: q(512)|s(128)
#define KVW    1024     // fp8 KV row: k(512B) | v(512B)

typedef __attribute__((ext_vector_type(8))) short short8v;
typedef __attribute__((ext_vector_type(8))) unsigned short ushort8v;
typedef __attribute__((ext_vector_type(4))) float floatx4;
typedef __attribute__((ext_vector_type(2))) float floatx2;
typedef __attribute__((ext_vector_type(2))) unsigned int uintx2;

__device__ inline float bf2f(unsigned short u) {
    return __uint_as_float(((unsigned)u) << 16);
}

template <bool HI>
__device__ inline floatx2 fp8x2_to_f32(unsigned int w) {
    return __builtin_amdgcn_cvt_pk_f32_fp8(w, HI);
}

__device__ inline unsigned char f32_to_fp8(float v) {
    return (unsigned char)(__builtin_amdgcn_cvt_pk_fp8_f32(v, v, 0, false) & 0xff);
}

// async global->LDS, 16 B per lane; lds dst = wave-uniform base + lane*16
__device__ inline void gload_lds16(const void* g, void* l) {
    __builtin_amdgcn_global_load_lds(
        (const __attribute__((address_space(1))) unsigned int*)g,
        (__attribute__((address_space(3))) unsigned int*)l, 16, 0, 0);
}

// ---------------- CSR build ----------------

__global__ void hist_kernel(const int* __restrict__ dst, int* __restrict__ deg, int E) {
    int e = blockIdx.x * 256 + threadIdx.x;
    if (e < E) atomicAdd(&deg[dst[e]], 1);
}

__global__ __launch_bounds__(1024) void scan_kernel(const int* __restrict__ deg,
                                                    int* __restrict__ indptr,
                                                    int* __restrict__ cursor, int n) {
    __shared__ int wavesum[16];
    __shared__ int carry_s;
    int t = threadIdx.x;
    int lane = t & 63;
    int w = t >> 6;
    if (t == 0) carry_s = 0;
    __syncthreads();
    for (int base = 0; base < n; base += 4096) {
        int idx = base + t * 4;
        int v0 = (idx + 0 < n) ? deg[idx + 0] : 0;
        int v1 = (idx + 1 < n) ? deg[idx + 1] : 0;
        int v2 = (idx + 2 < n) ? deg[idx + 2] : 0;
        int v3 = (idx + 3 < n) ? deg[idx + 3] : 0;
        int s1 = v0 + v1, s2 = s1 + v2, tot = s2 + v3;
        int x = tot;
        #pragma unroll
        for (int off = 1; off < 64; off <<= 1) {
            int y = __shfl_up(x, off);
            if (lane >= off) x += y;
        }
        if (lane == 63) wavesum[w] = x;
        __syncthreads();
        int woff = 0;
        for (int i = 0; i < w; i++) woff += wavesum[i];
        int carry = carry_s;
        int excl = carry + woff + x - tot;
        if (idx + 0 < n) { indptr[idx + 0] = excl;      cursor[idx + 0] = excl; }
        if (idx + 1 < n) { indptr[idx + 1] = excl + v0; cursor[idx + 1] = excl + v0; }
        if (idx + 2 < n) { indptr[idx + 2] = excl + s1; cursor[idx + 2] = excl + s1; }
        if (idx + 3 < n) { indptr[idx + 3] = excl + s2; cursor[idx + 3] = excl + s2; }
        __syncthreads();
        if (t == 0) {
            int s = 0;
            #pragma unroll
            for (int i = 0; i < 16; i++) s += wavesum[i];
            carry_s = carry + s;
        }
        __syncthreads();
    }
    if (t == 0) indptr[n] = carry_s;
}

__global__ void scatter_kernel(const int* __restrict__ src, const int* __restrict__ dst,
                               int* __restrict__ cursor, int* __restrict__ srcs_sorted, int E) {
    int e = blockIdx.x * 256 + threadIdx.x;
    if (e < E) {
        int d = dst[e];
        int pos = atomicAdd(&cursor[d], 1);
        srcs_sorted[pos] = src[e];
    }
}

// ---------------- prep: cast + transpose + concat weights ----------------

__global__ void cast_bf16_kernel(const float* __restrict__ in, __hip_bfloat16* __restrict__ out, int n) {
    int i = blockIdx.x * 256 + threadIdx.x;
    if (i < n) out[i] = __float2bfloat16(in[i]);
}

// L0: Wt[2048][128] from Wq/Wk/Wv/Ws [128][512]; bcat[2048]
__global__ void prep0_kernel(const float* __restrict__ Wq, const float* __restrict__ Wk,
                             const float* __restrict__ Wv, const float* __restrict__ Wsk,
                             const float* __restrict__ bq, const float* __restrict__ bk,
                             const float* __restrict__ bv, const float* __restrict__ bsk,
                             __hip_bfloat16* __restrict__ Wt, float* __restrict__ bcat) {
    int i = blockIdx.x * 256 + threadIdx.x;
    if (i < N0CAT * 128) {
        int n = i >> 7, k = i & 127;
        int sel = n >> 9, col = n & 511;
        const float* W = (sel == 0) ? Wq : (sel == 1) ? Wk : (sel == 2) ? Wv : Wsk;
        Wt[i] = __float2bfloat16(W[k * 512 + col]);
    }
    if (i < N0CAT) {
        int sel = i >> 9, col = i & 511;
        const float* b = (sel == 0) ? bq : (sel == 1) ? bk : (sel == 2) ? bv : bsk;
        bcat[i] = b[col];
    }
}

// L1: Wt[1664][512] from Wq/Wk/Wv [512][512] + Ws1 [512][128]; bcat[1664]
__global__ void prep1_kernel(const float* __restrict__ Wq, const float* __restrict__ Wk,
                             const float* __restrict__ Wv, const float* __restrict__ Wsk,
                             const float* __restrict__ bq, const float* __restrict__ bk,
                             const float* __restrict__ bv, const float* __restrict__ bsk,
                             __hip_bfloat16* __restrict__ Wt, float* __restrict__ bcat) {
    int i = blockIdx.x * 256 + threadIdx.x;
    if (i < N1CAT * 512) {
        int n = i >> 9, k = i & 511;
        float val;
        if (n < 1536) {
            int sel = n >> 9, col = n & 511;
            const float* W = (sel == 0) ? Wq : (sel == 1) ? Wk : Wv;
            val = W[k * 512 + col];
        } else {
            val = Wsk[k * 128 + (n - 1536)];
        }
        Wt[i] = __float2bfloat16(val);
    }
    if (i < N1CAT) {
        float bv_;
        if (i < 1536) {
            int sel = i >> 9, col = i & 511;
            const float* b = (sel == 0) ? bq : (sel == 1) ? bk : bv;
            bv_ = b[col];
        } else {
            bv_ = bsk[i - 1536];
        }
        bcat[i] = bv_;
    }
}

// ---------------- bf16 MFMA GEMM, async-LDS staging + XOR swizzle ----------------
// C = A[M,K] @ Bt[Nd,K]^T + bias. Columns: [0,512) q -> P; [512,1536) k|v -> KV8 fp8;
// [1536,Nd) s -> P offset 512+. Grid f = nt*mt_pad + mt => xcd(f%8)==mt%8.
// LDS layout swizzled: slot (row, c8) holds global (row, c8 ^ (row&7)) — dense rows
// (global_load_lds requires lane-contiguous dst), banks spread on read.

#define BM 128
#define BN 128
#define BK 64

__global__ __launch_bounds__(256) void gemm_mfma(const __hip_bfloat16* __restrict__ A,
                                                 const __hip_bfloat16* __restrict__ Bt,
                                                 const float* __restrict__ bias,
                                                 __hip_bfloat16* __restrict__ P,
                                                 int pstride,
                                                 unsigned char* __restrict__ KV8,
                                                 int M, int K, int Nd, int mt_pad) {
    __shared__ __hip_bfloat16 As[BM][BK];
    __shared__ __hip_bfloat16 Bs[BN][BK];
    int f = blockIdx.x;
    int mt = f % mt_pad, nt = f / mt_pad;
    int bm = mt * BM, bn = nt * BN;
    if (bm >= M) return;
    int t = threadIdx.x;
    int lane = t & 63, w = t >> 6;
    int quad = lane >> 4, l16 = lane & 15;
    int wm = (w >> 1) * 64, wn = (w & 1) * 64;

    // staging: slot (row = i*32 + w*8 + lane/8, c8 = lane&7) <- global c8g = (lane&7) ^ (lane/8 & 7)
    int srow = w * 8 + (lane >> 3);
    int c8g = (lane & 7) ^ ((lane >> 3) & 7);
    const char* Ab = (const char*)(A + (size_t)(bm + srow) * K + c8g * 8);
    const char* Bb = (const char*)(Bt + (size_t)(bn + srow) * K + c8g * 8);
    char* Al = (char*)&As[0][0] + w * 1024;
    char* Bl = (char*)&Bs[0][0] + w * 1024;

    int sw = l16 & 7;   // read-side swizzle key (row&7 == l16&7 for all fragments)

    floatx4 acc[4][4];
    #pragma unroll
    for (int i = 0; i < 4; i++)
        #pragma unroll
        for (int j = 0; j < 4; j++)
            acc[i][j] = (floatx4)0.0f;

    for (int k0 = 0; k0 < K; k0 += BK) {
        __syncthreads();   // previous compute done before overwrite
        #pragma unroll
        for (int i = 0; i < 4; i++) {
            size_t go = ((size_t)i * 32 * K + k0) * 2;
            gload_lds16(Ab + go, Al + i * 4096);
            gload_lds16(Bb + go, Bl + i * 4096);
        }
        __syncthreads();   // vmcnt drained -> LDS visible
        #pragma unroll
        for (int ks = 0; ks < BK; ks += 32) {
            int c8a = (quad + (ks >> 3)) ^ sw;   // swizzled 8-elem group index
            short8v af[4], bfr[4];
            #pragma unroll
            for (int i = 0; i < 4; i++)
                af[i] = *(const short8v*)&As[wm + i * 16 + l16][c8a * 8];
            #pragma unroll
            for (int j = 0; j < 4; j++)
                bfr[j] = *(const short8v*)&Bs[wn + j * 16 + l16][c8a * 8];
            #pragma unroll
            for (int i = 0; i < 4; i++)
                #pragma unroll
                for (int j = 0; j < 4; j++)
                    acc[i][j] = __builtin_amdgcn_mfma_f32_16x16x32_bf16(af[i], bfr[j], acc[i][j], 0, 0, 0);
        }
    }

    #pragma unroll
    for (int i = 0; i < 4; i++) {
        #pragma unroll
        for (int j = 0; j < 4; j++) {
            int col = bn + wn + j * 16 + l16;
            float bb = bias[col];
            if (col < 512) {
                #pragma unroll
                for (int r = 0; r < 4; r++) {
                    int row = bm + wm + i * 16 + quad * 4 + r;
                    if (row < M)
                        P[(size_t)row * pstride + col] = __float2bfloat16(acc[i][j][r] + bb);
                }
            } else if (col < 1536) {
                #pragma unroll
                for (int r = 0; r < 4; r++) {
                    int row = bm + wm + i * 16 + quad * 4 + r;
                    if (row < M)
                        KV8[(size_t)row * KVW + (col - 512)] = f32_to_fp8(acc[i][j][r] + bb);
                }
            } else {
                #pragma unroll
                for (int r = 0; r < 4; r++) {
                    int row = bm + wm + i * 16 + quad * 4 + r;
                    if (row < M)
                        P[(size_t)row * pstride + 512 + (col - 1536)] = __float2bfloat16(acc[i][j][r] + bb);
                }
            }
        }
    }
}

// ---------------- attention: fp8 K/V gather ----------------
// P row: [ q(512) | s ], KV8 row: [ k8(512B) | v8(512B) ].
// mode 0: out_b[n,512] = relu(attn_concat + s)   (bf16)
// mode 1: out_f[n,128] = mean_heads(attn) + s    (f32)

#define PF 4

__global__ __launch_bounds__(256) void attn_kernel(const __hip_bfloat16* __restrict__ P,
                                                   int pstride,
                                                   const unsigned char* __restrict__ KV8,
                                                   const int* __restrict__ indptr,
                                                   const int* __restrict__ srcs,
                                                   __hip_bfloat16* __restrict__ out_b,
                                                   float* __restrict__ out_f,
                                                   int n_nodes, int mode) {
    int wave = threadIdx.x >> 6;
    int lane = threadIdx.x & 63;
    int node = blockIdx.x * 4 + wave;
    if (node >= n_nodes) return;
    const float scale = 0.08838834764831845f;  // 1/sqrt(128)

    const __hip_bfloat16* Prow = P + (size_t)node * pstride;
    float qf[8];
    {
        ushort8v qu = *(const ushort8v*)(Prow + lane * 8);
        #pragma unroll
        for (int j = 0; j < 8; j++) qf[j] = bf2f(qu[j]);
    }

    float m = -INFINITY, l = 0.f;
    float acc[8] = {0.f, 0.f, 0.f, 0.f, 0.f, 0.f, 0.f, 0.f};

    int e0 = indptr[node], e1 = indptr[node + 1];
    const unsigned char* Kb = KV8 + lane * 8;        // K bytes for this lane

    uintx2 kb[PF], vb[PF];
    #pragma unroll
    for (int i = 0; i < PF; i++) {
        if (e0 + i < e1) {
            int s = srcs[e0 + i];
            const unsigned char* kp = Kb + (size_t)s * KVW;
            kb[i] = *(const uintx2*)kp;
            vb[i] = *(const uintx2*)(kp + 512);
        }
    }

    for (int e = e0; e < e1; e += PF) {
        #pragma unroll
        for (int i = 0; i < PF; i++) {
            int ce = e + i;
            if (ce < e1) {
                uintx2 ku = kb[i];
                uintx2 vu = vb[i];
                int pe = ce + PF;
                if (pe < e1) {
                    int s = srcs[pe];
                    const unsigned char* kp = Kb + (size_t)s * KVW;
                    kb[i] = *(const uintx2*)kp;
                    vb[i] = *(const uintx2*)(kp + 512);
                }
                floatx2 k01 = fp8x2_to_f32<false>(ku[0]);
                floatx2 k23 = fp8x2_to_f32<true >(ku[0]);
                floatx2 k45 = fp8x2_to_f32<false>(ku[1]);
                floatx2 k67 = fp8x2_to_f32<true >(ku[1]);
                float part = qf[0] * k01[0] + qf[1] * k01[1]
                           + qf[2] * k23[0] + qf[3] * k23[1]
                           + qf[4] * k45[0] + qf[5] * k45[1]
                           + qf[6] * k67[0] + qf[7] * k67[1];
                part += __shfl_xor(part, 1);
                part += __shfl_xor(part, 2);
                part += __shfl_xor(part, 4);
                part += __shfl_xor(part, 8);
                float logit = part * scale;
                float mnew = fmaxf(m, logit);
                float corr = __expf(m - mnew);
                float p = __expf(logit - mnew);
                l = l * corr + p;
                m = mnew;
                floatx2 v01 = fp8x2_to_f32<false>(vu[0]);
                floatx2 v23 = fp8x2_to_f32<true >(vu[0]);
                floatx2 v45 = fp8x2_to_f32<false>(vu[1]);
                floatx2 v67 = fp8x2_to_f32<true >(vu[1]);
                acc[0] = acc[0] * corr + p * v01[0];
                acc[1] = acc[1] * corr + p * v01[1];
                acc[2] = acc[2] * corr + p * v23[0];
                acc[3] = acc[3] * corr + p * v23[1];
                acc[4] = acc[4] * corr + p * v45[0];
                acc[5] = acc[5] * corr + p * v45[1];
                acc[6] = acc[6] * corr + p * v67[0];
                acc[7] = acc[7] * corr + p * v67[1];
            }
        }
    }
    float inv = (l > 0.f) ? 1.f / l : 0.f;

    if (mode == 0) {
        ushort8v su = *(const ushort8v*)(Prow + 512 + lane * 8);
        ushort8v o;
        #pragma unroll
        for (int j = 0; j < 8; j++) {
            float r = fmaxf(acc[j] * inv + bf2f(su[j]), 0.f);
            o[j] = (unsigned short)__bfloat16_as_ushort(__float2bfloat16(r));
        }
        *(ushort8v*)(out_b + (size_t)node * HCH + lane * 8) = o;
    } else {
        float r[8];
        #pragma unroll
        for (int j = 0; j < 8; j++) {
            r[j] = acc[j] * inv;
            r[j] += __shfl_xor(r[j], 16);
            r[j] += __shfl_xor(r[j], 32);
            r[j] *= 0.25f;
        }
        if (lane < 16) {
            const __hip_bfloat16* sp = Prow + 512 + lane * 8;
            float* op = out_f + (size_t)node * OUTD + lane * 8;
            #pragma unroll
            for (int j = 0; j < 8; j++) op[j] = r[j] + bf2f(__bfloat16_as_ushort(sp[j]));
        }
    }
}

// ---------------- launch ----------------

static inline size_t align256(size_t x) { return (x + 255) & ~(size_t)255; }

extern "C" void kernel_launch(void* const* d_in, const int* in_sizes, int n_in,
                              void* d_out, int out_size, void* d_ws, size_t ws_size,
                              hipStream_t stream) {
    const float* x   = (const float*)d_in[0];
    const int*   ei  = (const int*)d_in[1];
    const float* Wq0 = (const float*)d_in[2];  const float* bq0 = (const float*)d_in[3];
    const float* Wk0 = (const float*)d_in[4];  const float* bk0 = (const float*)d_in[5];
    const float* Wv0 = (const float*)d_in[6];  const float* bv0 = (const float*)d_in[7];
    const float* Ws0 = (const float*)d_in[8];  const float* bs0 = (const float*)d_in[9];
    const float* Wq1 = (const float*)d_in[10]; const float* bq1 = (const float*)d_in[11];
    const float* Wk1 = (const float*)d_in[12]; const float* bk1 = (const float*)d_in[13];
    const float* Wv1 = (const float*)d_in[14]; const float* bv1 = (const float*)d_in[15];
    const float* Ws1 = (const float*)d_in[16]; const float* bs1 = (const float*)d_in[17];
    float* out = (float*)d_out;

    const int N = in_sizes[0] / 128;        // 20000
    const int E = in_sizes[1] / 2;          // 320000
    const int* src = ei;
    const int* dst = ei + E;

    int mtiles = (N + BM - 1) / BM;          // 157
    int mt_pad = (mtiles + 7) & ~7;          // 160 (mult of 8 -> XCD affinity)
    const int Mpad = mt_pad * BM;            // 20480: A buffers padded for async staging

    char* ws = (char*)d_ws;
    __hip_bfloat16* P0  = (__hip_bfloat16*)ws; ws += align256((size_t)N * P0STR * 2);
    __hip_bfloat16* P1  = P0;                  // alias: P0 dead before P1 written
    __hip_bfloat16* Hbb = (__hip_bfloat16*)ws; ws += align256((size_t)Mpad * HCH * 2);
    __hip_bfloat16* Xb  = (__hip_bfloat16*)ws; ws += align256((size_t)Mpad * 128 * 2);
    unsigned char* KV8  = (unsigned char*)ws;  ws += align256((size_t)N * KVW);
    __hip_bfloat16* Wc0 = (__hip_bfloat16*)ws; ws += align256((size_t)N0CAT * 128 * 2);
    __hip_bfloat16* Wc1 = (__hip_bfloat16*)ws; ws += align256((size_t)N1CAT * 512 * 2);
    float* bc0 = (float*)ws; ws += align256((size_t)N0CAT * 4);
    float* bc1 = (float*)ws; ws += align256((size_t)N1CAT * 4);
    int* deg    = (int*)ws; ws += align256((size_t)N * 4);
    int* cursor = (int*)ws; ws += align256((size_t)N * 4);
    int* indptr = (int*)ws; ws += align256((size_t)(N + 2) * 4);
    int* srcs   = (int*)ws; ws += align256((size_t)E * 4);

    dim3 blk(256);

    // --- CSR build ---
    (void)hipMemsetAsync(deg, 0, (size_t)N * 4, stream);
    hist_kernel<<<(E + 255) / 256, 256, 0, stream>>>(dst, deg, E);
    scan_kernel<<<1, 1024, 0, stream>>>(deg, indptr, cursor, N);
    scatter_kernel<<<(E + 255) / 256, 256, 0, stream>>>(src, dst, cursor, srcs, E);

    // --- prep ---
    cast_bf16_kernel<<<((size_t)N * 128 + 255) / 256, blk, 0, stream>>>(x, Xb, N * 128);
    prep0_kernel<<<(N0CAT * 128 + 255) / 256, blk, 0, stream>>>(Wq0, Wk0, Wv0, Ws0, bq0, bk0, bv0, bs0, Wc0, bc0);
    prep1_kernel<<<(N1CAT * 512 + 255) / 256, blk, 0, stream>>>(Wq1, Wk1, Wv1, Ws1, bq1, bk1, bv1, bs1, Wc1, bc1);

    // --- layer 0: fused projections (q->P0, kv->fp8 KV8, s->P0) + attention ---
    gemm_mfma<<<dim3(mt_pad * (N0CAT / BN)), blk, 0, stream>>>(
        Xb, Wc0, bc0, P0, P0STR, KV8, N, 128, N0CAT, mt_pad);
    attn_kernel<<<(N + 3) / 4, blk, 0, stream>>>(P0, P0STR, KV8, indptr, srcs, Hbb, nullptr, N, 0);

    // --- layer 1: fused projections + attention ---
    gemm_mfma<<<dim3(mt_pad * (N1CAT / BN)), blk, 0, stream>>>(
        Hbb, Wc1, bc1, P1, P1STR, KV8, N, 512, N1CAT, mt_pad);
    attn_kernel<<<(N + 3) / 4, blk, 0, stream>>>(P1, P1STR, KV8, indptr, srcs, nullptr, out, N, 1);
}

// Round 10
// 374.799 us; speedup vs baseline: 1.1205x; 1.0249x over previous
//
#include <hip/hip_runtime.h>
#include <hip/hip_bf16.h>
#include <math.h>

#define HCH    512      // H * HID = 4 * 128
#define OUTD   128
#define N0CAT  2048     // L0 fused: q|k|v|s   (s = 512)
#define N1CAT  1664     // L1 fused: q|k|v|s1  (s = 128)
#define P0STR  1024     // P0 row: q(512)|s(512)
#define P1STR  640      // P1 row: q(512)|s(128)
#define KVW    1024     // fp8 KV row: k(512B) | v(512B)

typedef __attribute__((ext_vector_type(8))) short short8v;
typedef __attribute__((ext_vector_type(8))) unsigned short ushort8v;
typedef __attribute__((ext_vector_type(4))) unsigned short ushort4v;
typedef __attribute__((ext_vector_type(4))) float floatx4;
typedef __attribute__((ext_vector_type(2))) float floatx2;
typedef __attribute__((ext_vector_type(2))) unsigned int uintx2;

__device__ inline float bf2f(unsigned short u) {
    return __uint_as_float(((unsigned)u) << 16);
}

__device__ inline unsigned short f2bf(float f) {
    return (unsigned short)__bfloat16_as_ushort(__float2bfloat16(f));
}

template <bool HI>
__device__ inline floatx2 fp8x2_to_f32(unsigned int w) {
    return __builtin_amdgcn_cvt_pk_f32_fp8(w, HI);
}

__device__ inline unsigned int f32x4_to_fp8(float a, float b, float c, float d) {
    int w = __builtin_amdgcn_cvt_pk_fp8_f32(a, b, 0, false);
    w = __builtin_amdgcn_cvt_pk_fp8_f32(c, d, w, true);
    return (unsigned int)w;
}

// async global->LDS, 16 B per lane; lds dst = wave-uniform base + lane*16
__device__ inline void gload_lds16(const void* g, void* l) {
    __builtin_amdgcn_global_load_lds(
        (const __attribute__((address_space(1))) unsigned int*)g,
        (__attribute__((address_space(3))) unsigned int*)l, 16, 0, 0);
}

// ---------------- CSR build ----------------

__global__ void hist_kernel(const int* __restrict__ dst, int* __restrict__ deg, int E) {
    int e = blockIdx.x * 256 + threadIdx.x;
    if (e < E) atomicAdd(&deg[dst[e]], 1);
}

__global__ __launch_bounds__(1024) void scan_kernel(const int* __restrict__ deg,
                                                    int* __restrict__ indptr,
                                                    int* __restrict__ cursor, int n) {
    __shared__ int wavesum[16];
    __shared__ int carry_s;
    int t = threadIdx.x;
    int lane = t & 63;
    int w = t >> 6;
    if (t == 0) carry_s = 0;
    __syncthreads();
    for (int base = 0; base < n; base += 4096) {
        int idx = base + t * 4;
        int v0 = (idx + 0 < n) ? deg[idx + 0] : 0;
        int v1 = (idx + 1 < n) ? deg[idx + 1] : 0;
        int v2 = (idx + 2 < n) ? deg[idx + 2] : 0;
        int v3 = (idx + 3 < n) ? deg[idx + 3] : 0;
        int s1 = v0 + v1, s2 = s1 + v2, tot = s2 + v3;
        int x = tot;
        #pragma unroll
        for (int off = 1; off < 64; off <<= 1) {
            int y = __shfl_up(x, off);
            if (lane >= off) x += y;
        }
        if (lane == 63) wavesum[w] = x;
        __syncthreads();
        int woff = 0;
        for (int i = 0; i < w; i++) woff += wavesum[i];
        int carry = carry_s;
        int excl = carry + woff + x - tot;
        if (idx + 0 < n) { indptr[idx + 0] = excl;      cursor[idx + 0] = excl; }
        if (idx + 1 < n) { indptr[idx + 1] = excl + v0; cursor[idx + 1] = excl + v0; }
        if (idx + 2 < n) { indptr[idx + 2] = excl + s1; cursor[idx + 2] = excl + s1; }
        if (idx + 3 < n) { indptr[idx + 3] = excl + s2; cursor[idx + 3] = excl + s2; }
        __syncthreads();
        if (t == 0) {
            int s = 0;
            #pragma unroll
            for (int i = 0; i < 16; i++) s += wavesum[i];
            carry_s = carry + s;
        }
        __syncthreads();
    }
    if (t == 0) indptr[n] = carry_s;
}

__global__ void scatter_kernel(const int* __restrict__ src, const int* __restrict__ dst,
                               int* __restrict__ cursor, int* __restrict__ srcs_sorted, int E) {
    int e = blockIdx.x * 256 + threadIdx.x;
    if (e < E) {
        int d = dst[e];
        int pos = atomicAdd(&cursor[d], 1);
        srcs_sorted[pos] = src[e];
    }
}

// ---------------- prep: cast + transpose + concat weights ----------------

__global__ void cast_bf16_kernel(const float* __restrict__ in, __hip_bfloat16* __restrict__ out, int n) {
    int i = blockIdx.x * 256 + threadIdx.x;
    if (i < n) out[i] = __float2bfloat16(in[i]);
}

// L0: Wt[2048][128] from Wq/Wk/Wv/Ws [128][512]; bcat[2048]
__global__ void prep0_kernel(const float* __restrict__ Wq, const float* __restrict__ Wk,
                             const float* __restrict__ Wv, const float* __restrict__ Wsk,
                             const float* __restrict__ bq, const float* __restrict__ bk,
                             const float* __restrict__ bv, const float* __restrict__ bsk,
                             __hip_bfloat16* __restrict__ Wt, float* __restrict__ bcat) {
    int i = blockIdx.x * 256 + threadIdx.x;
    if (i < N0CAT * 128) {
        int n = i >> 7, k = i & 127;
        int sel = n >> 9, col = n & 511;
        const float* W = (sel == 0) ? Wq : (sel == 1) ? Wk : (sel == 2) ? Wv : Wsk;
        Wt[i] = __float2bfloat16(W[k * 512 + col]);
    }
    if (i < N0CAT) {
        int sel = i >> 9, col = i & 511;
        const float* b = (sel == 0) ? bq : (sel == 1) ? bk : (sel == 2) ? bv : bsk;
        bcat[i] = b[col];
    }
}

// L1: Wt[1664][512] from Wq/Wk/Wv [512][512] + Ws1 [512][128]; bcat[1664]
__global__ void prep1_kernel(const float* __restrict__ Wq, const float* __restrict__ Wk,
                             const float* __restrict__ Wv, const float* __restrict__ Wsk,
                             const float* __restrict__ bq, const float* __restrict__ bk,
                             const float* __restrict__ bv, const float* __restrict__ bsk,
                             __hip_bfloat16* __restrict__ Wt, float* __restrict__ bcat) {
    int i = blockIdx.x * 256 + threadIdx.x;
    if (i < N1CAT * 512) {
        int n = i >> 9, k = i & 511;
        float val;
        if (n < 1536) {
            int sel = n >> 9, col = n & 511;
            const float* W = (sel == 0) ? Wq : (sel == 1) ? Wk : Wv;
            val = W[k * 512 + col];
        } else {
            val = Wsk[k * 128 + (n - 1536)];
        }
        Wt[i] = __float2bfloat16(val);
    }
    if (i < N1CAT) {
        float bv_;
        if (i < 1536) {
            int sel = i >> 9, col = i & 511;
            const float* b = (sel == 0) ? bq : (sel == 1) ? bk : bv;
            bv_ = b[col];
        } else {
            bv_ = bsk[i - 1536];
        }
        bcat[i] = bv_;
    }
}

// ---------------- bf16 MFMA GEMM, async-LDS + XOR swizzle + transposed acc ----------------
// C = A[M,K] @ Bt[Nd,K]^T + bias. Operand-swapped MFMA: acc[i][j] holds, per lane,
// row = wm+i*16+l16 and 4 consecutive cols wn+j*16+quad*4.. -> vector stores.
// Columns: [0,512) q -> P; [512,1536) k|v -> KV8 fp8; [1536,Nd) s -> P offset 512+.
// Grid f = nt*mt_pad + mt => xcd(f%8)==mt%8 (A-tile L2 affinity).

#define BM 128
#define BN 128
#define BK 64

__global__ __launch_bounds__(256) void gemm_mfma(const __hip_bfloat16* __restrict__ A,
                                                 const __hip_bfloat16* __restrict__ Bt,
                                                 const float* __restrict__ bias,
                                                 __hip_bfloat16* __restrict__ P,
                                                 int pstride,
                                                 unsigned char* __restrict__ KV8,
                                                 int M, int K, int Nd, int mt_pad) {
    __shared__ __hip_bfloat16 As[BM][BK];
    __shared__ __hip_bfloat16 Bs[BN][BK];
    int f = blockIdx.x;
    int mt = f % mt_pad, nt = f / mt_pad;
    int bm = mt * BM, bn = nt * BN;
    if (bm >= M) return;
    int t = threadIdx.x;
    int lane = t & 63, w = t >> 6;
    int quad = lane >> 4, l16 = lane & 15;
    int wm = (w >> 1) * 64, wn = (w & 1) * 64;

    // staging: slot (row = i*32 + w*8 + lane/8, c8 = lane&7) <- global c8g = (lane&7) ^ (lane/8 & 7)
    int srow = w * 8 + (lane >> 3);
    int c8g = (lane & 7) ^ ((lane >> 3) & 7);
    const char* Ab = (const char*)(A + (size_t)(bm + srow) * K + c8g * 8);
    const char* Bb = (const char*)(Bt + (size_t)(bn + srow) * K + c8g * 8);
    char* Al = (char*)&As[0][0] + w * 1024;
    char* Bl = (char*)&Bs[0][0] + w * 1024;

    int sw = l16 & 7;   // read-side swizzle key (row&7 == l16&7 for all fragments)

    floatx4 acc[4][4];
    #pragma unroll
    for (int i = 0; i < 4; i++)
        #pragma unroll
        for (int j = 0; j < 4; j++)
            acc[i][j] = (floatx4)0.0f;

    for (int k0 = 0; k0 < K; k0 += BK) {
        __syncthreads();   // previous compute done before overwrite
        #pragma unroll
        for (int i = 0; i < 4; i++) {
            size_t go = ((size_t)i * 32 * K + k0) * 2;
            gload_lds16(Ab + go, Al + i * 4096);
            gload_lds16(Bb + go, Bl + i * 4096);
        }
        __syncthreads();   // vmcnt drained -> LDS visible
        #pragma unroll
        for (int ks = 0; ks < BK; ks += 32) {
            int c8a = (quad + (ks >> 3)) ^ sw;   // swizzled 8-elem group index
            short8v af[4], bfr[4];
            #pragma unroll
            for (int i = 0; i < 4; i++)
                af[i] = *(const short8v*)&As[wm + i * 16 + l16][c8a * 8];
            #pragma unroll
            for (int j = 0; j < 4; j++)
                bfr[j] = *(const short8v*)&Bs[wn + j * 16 + l16][c8a * 8];
            // swapped operands: D' = Bt_frag x A_frag  =>  lane holds one row, 4 consecutive cols
            #pragma unroll
            for (int i = 0; i < 4; i++)
                #pragma unroll
                for (int j = 0; j < 4; j++)
                    acc[i][j] = __builtin_amdgcn_mfma_f32_16x16x32_bf16(bfr[j], af[i], acc[i][j], 0, 0, 0);
        }
    }

    // epilogue: row = bm+wm+i*16+l16; cols = bn+wn+j*16+quad*4 .. +3 (never cross 512-boundaries)
    #pragma unroll
    for (int i = 0; i < 4; i++) {
        int row = bm + wm + i * 16 + l16;
        if (row >= M) continue;
        #pragma unroll
        for (int j = 0; j < 4; j++) {
            int col = bn + wn + j * 16 + quad * 4;
            floatx4 bv = *(const floatx4*)(bias + col);
            float v0 = acc[i][j][0] + bv[0];
            float v1 = acc[i][j][1] + bv[1];
            float v2 = acc[i][j][2] + bv[2];
            float v3 = acc[i][j][3] + bv[3];
            if (col < 512) {
                ushort4v o = { f2bf(v0), f2bf(v1), f2bf(v2), f2bf(v3) };
                *(ushort4v*)(P + (size_t)row * pstride + col) = o;
            } else if (col < 1536) {
                *(unsigned int*)(KV8 + (size_t)row * KVW + (col - 512)) = f32x4_to_fp8(v0, v1, v2, v3);
            } else {
                ushort4v o = { f2bf(v0), f2bf(v1), f2bf(v2), f2bf(v3) };
                *(ushort4v*)(P + (size_t)row * pstride + 512 + (col - 1536)) = o;
            }
        }
    }
}

// ---------------- attention: fp8 K/V gather ----------------
// P row: [ q(512) | s ], KV8 row: [ k8(512B) | v8(512B) ].
// mode 0: out_b[n,512] = relu(attn_concat + s)   (bf16)
// mode 1: out_f[n,128] = mean_heads(attn) + s    (f32)

#define PF 4

__global__ __launch_bounds__(256) void attn_kernel(const __hip_bfloat16* __restrict__ P,
                                                   int pstride,
                                                   const unsigned char* __restrict__ KV8,
                                                   const int* __restrict__ indptr,
                                                   const int* __restrict__ srcs,
                                                   __hip_bfloat16* __restrict__ out_b,
                                                   float* __restrict__ out_f,
                                                   int n_nodes, int mode) {
    int wave = threadIdx.x >> 6;
    int lane = threadIdx.x & 63;
    int node = blockIdx.x * 4 + wave;
    if (node >= n_nodes) return;
    const float scale = 0.08838834764831845f;  // 1/sqrt(128)

    const __hip_bfloat16* Prow = P + (size_t)node * pstride;
    float qf[8];
    {
        ushort8v qu = *(const ushort8v*)(Prow + lane * 8);
        #pragma unroll
        for (int j = 0; j < 8; j++) qf[j] = bf2f(qu[j]);
    }

    float m = -INFINITY, l = 0.f;
    float acc[8] = {0.f, 0.f, 0.f, 0.f, 0.f, 0.f, 0.f, 0.f};

    int e0 = indptr[node], e1 = indptr[node + 1];
    const unsigned char* Kb = KV8 + lane * 8;        // K bytes for this lane

    uintx2 kb[PF], vb[PF];
    #pragma unroll
    for (int i = 0; i < PF; i++) {
        if (e0 + i < e1) {
            int s = srcs[e0 + i];
            const unsigned char* kp = Kb + (size_t)s * KVW;
            kb[i] = *(const uintx2*)kp;
            vb[i] = *(const uintx2*)(kp + 512);
        }
    }

    for (int e = e0; e < e1; e += PF) {
        #pragma unroll
        for (int i = 0; i < PF; i++) {
            int ce = e + i;
            if (ce < e1) {
                uintx2 ku = kb[i];
                uintx2 vu = vb[i];
                int pe = ce + PF;
                if (pe < e1) {
                    int s = srcs[pe];
                    const unsigned char* kp = Kb + (size_t)s * KVW;
                    kb[i] = *(const uintx2*)kp;
                    vb[i] = *(const uintx2*)(kp + 512);
                }
                floatx2 k01 = fp8x2_to_f32<false>(ku[0]);
                floatx2 k23 = fp8x2_to_f32<true >(ku[0]);
                floatx2 k45 = fp8x2_to_f32<false>(ku[1]);
                floatx2 k67 = fp8x2_to_f32<true >(ku[1]);
                float part = qf[0] * k01[0] + qf[1] * k01[1]
                           + qf[2] * k23[0] + qf[3] * k23[1]
                           + qf[4] * k45[0] + qf[5] * k45[1]
                           + qf[6] * k67[0] + qf[7] * k67[1];
                part += __shfl_xor(part, 1);
                part += __shfl_xor(part, 2);
                part += __shfl_xor(part, 4);
                part += __shfl_xor(part, 8);
                float logit = part * scale;
                float mnew = fmaxf(m, logit);
                float corr = __expf(m - mnew);
                float p = __expf(logit - mnew);
                l = l * corr + p;
                m = mnew;
                floatx2 v01 = fp8x2_to_f32<false>(vu[0]);
                floatx2 v23 = fp8x2_to_f32<true >(vu[0]);
                floatx2 v45 = fp8x2_to_f32<false>(vu[1]);
                floatx2 v67 = fp8x2_to_f32<true >(vu[1]);
                acc[0] = acc[0] * corr + p * v01[0];
                acc[1] = acc[1] * corr + p * v01[1];
                acc[2] = acc[2] * corr + p * v23[0];
                acc[3] = acc[3] * corr + p * v23[1];
                acc[4] = acc[4] * corr + p * v45[0];
                acc[5] = acc[5] * corr + p * v45[1];
                acc[6] = acc[6] * corr + p * v67[0];
                acc[7] = acc[7] * corr + p * v67[1];
            }
        }
    }
    float inv = (l > 0.f) ? 1.f / l : 0.f;

    if (mode == 0) {
        ushort8v su = *(const ushort8v*)(Prow + 512 + lane * 8);
        ushort8v o;
        #pragma unroll
        for (int j = 0; j < 8; j++) {
            float r = fmaxf(acc[j] * inv + bf2f(su[j]), 0.f);
            o[j] = f2bf(r);
        }
        *(ushort8v*)(out_b + (size_t)node * HCH + lane * 8) = o;
    } else {
        float r[8];
        #pragma unroll
        for (int j = 0; j < 8; j++) {
            r[j] = acc[j] * inv;
            r[j] += __shfl_xor(r[j], 16);
            r[j] += __shfl_xor(r[j], 32);
            r[j] *= 0.25f;
        }
        if (lane < 16) {
            const __hip_bfloat16* sp = Prow + 512 + lane * 8;
            float* op = out_f + (size_t)node * OUTD + lane * 8;
            #pragma unroll
            for (int j = 0; j < 8; j++) op[j] = r[j] + bf2f(__bfloat16_as_ushort(sp[j]));
        }
    }
}

// ---------------- launch ----------------

static inline size_t align256(size_t x) { return (x + 255) & ~(size_t)255; }

extern "C" void kernel_launch(void* const* d_in, const int* in_sizes, int n_in,
                              void* d_out, int out_size, void* d_ws, size_t ws_size,
                              hipStream_t stream) {
    const float* x   = (const float*)d_in[0];
    const int*   ei  = (const int*)d_in[1];
    const float* Wq0 = (const float*)d_in[2];  const float* bq0 = (const float*)d_in[3];
    const float* Wk0 = (const float*)d_in[4];  const float* bk0 = (const float*)d_in[5];
    const float* Wv0 = (const float*)d_in[6];  const float* bv0 = (const float*)d_in[7];
    const float* Ws0 = (const float*)d_in[8];  const float* bs0 = (const float*)d_in[9];
    const float* Wq1 = (const float*)d_in[10]; const float* bq1 = (const float*)d_in[11];
    const float* Wk1 = (const float*)d_in[12]; const float* bk1 = (const float*)d_in[13];
    const float* Wv1 = (const float*)d_in[14]; const float* bv1 = (const float*)d_in[15];
    const float* Ws1 = (const float*)d_in[16]; const float* bs1 = (const float*)d_in[17];
    float* out = (float*)d_out;

    const int N = in_sizes[0] / 128;        // 20000
    const int E = in_sizes[1] / 2;          // 320000
    const int* src = ei;
    const int* dst = ei + E;

    int mtiles = (N + BM - 1) / BM;          // 157
    int mt_pad = (mtiles + 7) & ~7;          // 160 (mult of 8 -> XCD affinity)
    const int Mpad = mt_pad * BM;            // 20480: A buffers padded for async staging

    char* ws = (char*)d_ws;
    __hip_bfloat16* P0  = (__hip_bfloat16*)ws; ws += align256((size_t)N * P0STR * 2);
    __hip_bfloat16* P1  = P0;                  // alias: P0 dead before P1 written
    __hip_bfloat16* Hbb = (__hip_bfloat16*)ws; ws += align256((size_t)Mpad * HCH * 2);
    __hip_bfloat16* Xb  = (__hip_bfloat16*)ws; ws += align256((size_t)Mpad * 128 * 2);
    unsigned char* KV8  = (unsigned char*)ws;  ws += align256((size_t)N * KVW);
    __hip_bfloat16* Wc0 = (__hip_bfloat16*)ws; ws += align256((size_t)N0CAT * 128 * 2);
    __hip_bfloat16* Wc1 = (__hip_bfloat16*)ws; ws += align256((size_t)N1CAT * 512 * 2);
    float* bc0 = (float*)ws; ws += align256((size_t)N0CAT * 4);
    float* bc1 = (float*)ws; ws += align256((size_t)N1CAT * 4);
    int* deg    = (int*)ws; ws += align256((size_t)N * 4);
    int* cursor = (int*)ws; ws += align256((size_t)N * 4);
    int* indptr = (int*)ws; ws += align256((size_t)(N + 2) * 4);
    int* srcs   = (int*)ws; ws += align256((size_t)E * 4);

    dim3 blk(256);

    // --- CSR build ---
    (void)hipMemsetAsync(deg, 0, (size_t)N * 4, stream);
    hist_kernel<<<(E + 255) / 256, 256, 0, stream>>>(dst, deg, E);
    scan_kernel<<<1, 1024, 0, stream>>>(deg, indptr, cursor, N);
    scatter_kernel<<<(E + 255) / 256, 256, 0, stream>>>(src, dst, cursor, srcs, E);

    // --- prep ---
    cast_bf16_kernel<<<((size_t)N * 128 + 255) / 256, blk, 0, stream>>>(x, Xb, N * 128);
    prep0_kernel<<<(N0CAT * 128 + 255) / 256, blk, 0, stream>>>(Wq0, Wk0, Wv0, Ws0, bq0, bk0, bv0, bs0, Wc0, bc0);
    prep1_kernel<<<(N1CAT * 512 + 255) / 256, blk, 0, stream>>>(Wq1, Wk1, Wv1, Ws1, bq1, bk1, bv1, bs1, Wc1, bc1);

    // --- layer 0: fused projections (q->P0, kv->fp8 KV8, s->P0) + attention ---
    gemm_mfma<<<dim3(mt_pad * (N0CAT / BN)), blk, 0, stream>>>(
        Xb, Wc0, bc0, P0, P0STR, KV8, N, 128, N0CAT, mt_pad);
    attn_kernel<<<(N + 3) / 4, blk, 0, stream>>>(P0, P0STR, KV8, indptr, srcs, Hbb, nullptr, N, 0);

    // --- layer 1: fused projections + attention ---
    gemm_mfma<<<dim3(mt_pad * (N1CAT / BN)), blk, 0, stream>>>(
        Hbb, Wc1, bc1, P1, P1STR, KV8, N, 512, N1CAT, mt_pad);
    attn_kernel<<<(N + 3) / 4, blk, 0, stream>>>(P1, P1STR, KV8, indptr, srcs, nullptr, out, N, 1);
}